// Round 5
// baseline (621.733 us; speedup 1.0000x reference)
//
#include <hip/hip_runtime.h>

#define N_NODES 100000
#define N_EDGES 1600000
#define D_IN    256
#define D_HID   64
#define D_OUT   32
#define NPROP   10

#define NBUCK 196          // bucket = row >> 9 (512 rows/bucket)
#define CHUNK 6080         // edges per bscatter block (LDS-limited)
#define NCHUNK ((N_EDGES + CHUNK - 1) / CHUNK)   // 264

typedef _Float16 half_t;
typedef _Float16 h8  __attribute__((ext_vector_type(8)));
typedef _Float16 h4  __attribute__((ext_vector_type(4)));
typedef float    f4v __attribute__((ext_vector_type(4)));
typedef int      i4v __attribute__((ext_vector_type(4)));

// ---------------- weight pack ----------------
__global__ __launch_bounds__(256) void pack_kernel(
    const float* __restrict__ W1, const float* __restrict__ W2,
    half_t* __restrict__ W1T, half_t* __restrict__ W2T)
{
  int t = blockIdx.x * 256 + threadIdx.x;
  if (t < 64 * 256) { int n = t >> 8, k = t & 255; W1T[t] = (half_t)W1[k * 64 + n]; }
  if (t < 32 * 64)  { int n = t >> 6, k = t & 63;  W2T[t] = (half_t)W2[k * 32 + n]; }
}

// ---------------- MLP head via MFMA (round-1 known-good: 59 us) ----------------
// Each WAVE owns 16 nodes x full 64 hid (4 hid-tiles, 32 MFMAs stage-1 +
// 4 MFMAs stage-2). F read exactly once; A-frags reused across 4 B-tiles.
#define HSTRIDE 72

__global__ __launch_bounds__(256, 4) void mlp_kernel(
    const float* __restrict__ F, const half_t* __restrict__ W1T,
    const float* __restrict__ b1, const half_t* __restrict__ W2T,
    const float* __restrict__ b2, half_t* __restrict__ x0h)
{
  __shared__ half_t h_lds[4 * 16 * HSTRIDE];   // per-wave 16x64 hidden (pad 72)
  __shared__ half_t out_lds[4 * 16 * 32];      // per-wave 16x32 output
  int t = threadIdx.x;
  int w = t >> 6, lane = t & 63;
  int m = lane & 15, q = lane >> 4;
  int gw = blockIdx.x * 4 + w;
  int node0 = gw * 16;
  if (node0 > N_NODES - 16) node0 = N_NODES - 16;  // tail waves duplicate last tile

  f4v acc[4];
#pragma unroll
  for (int i = 0; i < 4; ++i) acc[i] = (f4v){0.f, 0.f, 0.f, 0.f};

  const float* ap = F + (size_t)(node0 + m) * D_IN + q * 8;

#pragma unroll
  for (int h = 0; h < 2; ++h) {
    h8 af[4];
#pragma unroll
    for (int s = 0; s < 4; ++s) {
      float4 f0 = *(const float4*)(ap + h * 128 + s * 32);
      float4 f1 = *(const float4*)(ap + h * 128 + s * 32 + 4);
      h8 a;
      a[0] = (_Float16)f0.x; a[1] = (_Float16)f0.y;
      a[2] = (_Float16)f0.z; a[3] = (_Float16)f0.w;
      a[4] = (_Float16)f1.x; a[5] = (_Float16)f1.y;
      a[6] = (_Float16)f1.z; a[7] = (_Float16)f1.w;
      af[s] = a;
    }
    const half_t* bp = W1T + (size_t)m * D_IN + h * 128 + q * 8;
#pragma unroll
    for (int s = 0; s < 4; ++s) {
      h8 b0 = *(const h8*)(bp + 0 * 16 * D_IN + s * 32);
      h8 b1v = *(const h8*)(bp + 1 * 16 * D_IN + s * 32);
      h8 b2v = *(const h8*)(bp + 2 * 16 * D_IN + s * 32);
      h8 b3v = *(const h8*)(bp + 3 * 16 * D_IN + s * 32);
      acc[0] = __builtin_amdgcn_mfma_f32_16x16x32_f16(af[s], b0, acc[0], 0, 0, 0);
      acc[1] = __builtin_amdgcn_mfma_f32_16x16x32_f16(af[s], b1v, acc[1], 0, 0, 0);
      acc[2] = __builtin_amdgcn_mfma_f32_16x16x32_f16(af[s], b2v, acc[2], 0, 0, 0);
      acc[3] = __builtin_amdgcn_mfma_f32_16x16x32_f16(af[s], b3v, acc[3], 0, 0, 0);
    }
  }

  half_t* hw = h_lds + w * 16 * HSTRIDE;
#pragma unroll
  for (int ht = 0; ht < 4; ++ht) {
    float bb = b1[ht * 16 + m];
#pragma unroll
    for (int i = 0; i < 4; ++i) {
      float hv = fmaxf(acc[ht][i] + bb, 0.f);
      hw[(q * 4 + i) * HSTRIDE + ht * 16 + m] = (half_t)hv;
    }
  }
  __syncthreads();

  f4v o0 = {0.f, 0.f, 0.f, 0.f}, o1 = {0.f, 0.f, 0.f, 0.f};
#pragma unroll
  for (int s = 0; s < 2; ++s) {
    h8 a = *(const h8*)(hw + m * HSTRIDE + s * 32 + q * 8);
    h8 bb0 = *(const h8*)(W2T + (size_t)m * D_HID + s * 32 + q * 8);
    h8 bb1 = *(const h8*)(W2T + (size_t)(16 + m) * D_HID + s * 32 + q * 8);
    o0 = __builtin_amdgcn_mfma_f32_16x16x32_f16(a, bb0, o0, 0, 0, 0);
    o1 = __builtin_amdgcn_mfma_f32_16x16x32_f16(a, bb1, o1, 0, 0, 0);
  }
  half_t* ow = out_lds + w * 16 * 32;
  {
    float c0 = b2[m], c1 = b2[16 + m];
#pragma unroll
    for (int i = 0; i < 4; ++i) {
      ow[(q * 4 + i) * 32 + m]      = (half_t)(o0[i] + c0);
      ow[(q * 4 + i) * 32 + 16 + m] = (half_t)(o1[i] + c1);
    }
  }
  __syncthreads();

  {
    int nl = lane >> 2, qq = lane & 3;
    *(int4*)(x0h + (size_t)(node0 + nl) * D_OUT + qq * 8) =
        *(const int4*)(ow + nl * 32 + qq * 8);
  }
}

// ---------------- CSR build, two-pass bucketed sort ----------------
__global__ __launch_bounds__(256) void bhist_kernel(
    const int* __restrict__ row, int* __restrict__ bcnt)
{
  __shared__ int lb[NBUCK];
  int t = threadIdx.x;
  for (int i = t; i < NBUCK; i += 256) lb[i] = 0;
  __syncthreads();
  int stride = gridDim.x * 256;
  for (int e = blockIdx.x * 256 + t; e < N_EDGES; e += stride)
    atomicAdd(&lb[row[e] >> 9], 1);
  __syncthreads();
  for (int i = t; i < NBUCK; i += 256)
    if (lb[i]) atomicAdd(&bcnt[i], lb[i]);
}

// Reserve per bucket: align8(cnt) + 7*512 (worst per-row pad-to-8; slack
// redistributed exactly in bsort so layout stays hole-free).
__global__ __launch_bounds__(256) void bscan_kernel(
    const int* __restrict__ bcnt, int* __restrict__ bbase, int* __restrict__ pbase)
{
  __shared__ int l1[256], l2[256];
  int t = threadIdx.x;
  int a = (t < NBUCK) ? bcnt[t] : 0;
  int r = (t < NBUCK) ? (((a + 7) & ~7) + 7 * 512) : 0;
  l1[t] = a; l2[t] = r;
  __syncthreads();
  for (int off = 1; off < 256; off <<= 1) {
    int x1 = (t >= off) ? l1[t - off] : 0;
    int x2 = (t >= off) ? l2[t - off] : 0;
    __syncthreads();
    l1[t] += x1; l2[t] += x2;
    __syncthreads();
  }
  if (t < NBUCK) { bbase[t] = l1[t] - a; pbase[t] = l2[t] - r; }
  if (t == NBUCK - 1) { bbase[NBUCK] = l1[t]; pbase[NBUCK] = l2[t]; }
}

__global__ __launch_bounds__(256) void bscatter_kernel(
    const int* __restrict__ row, const int* __restrict__ col,
    const float* __restrict__ vals, int* __restrict__ bfill,
    const int* __restrict__ bbase, int2* __restrict__ ebuck)
{
  __shared__ int2 img[CHUNK];                 // 48,640 B
  __shared__ unsigned short sbk[CHUNK];       // 12,160 B
  __shared__ int cnt[NBUCK], base[NBUCK], gb[NBUCK], fil[NBUCK];
  __shared__ int ssc[256];
  int t = threadIdx.x;
  int e0 = blockIdx.x * CHUNK;
  int n = min(CHUNK, N_EDGES - e0);

  for (int i = t; i < NBUCK; i += 256) { cnt[i] = 0; fil[i] = 0; }
  __syncthreads();
  for (int i = t; i < n; i += 256) atomicAdd(&cnt[row[e0 + i] >> 9], 1);
  __syncthreads();
  int c = (t < NBUCK) ? cnt[t] : 0;
  ssc[t] = c;
  __syncthreads();
  for (int off = 1; off < 256; off <<= 1) {
    int add = (t >= off) ? ssc[t - off] : 0;
    __syncthreads();
    ssc[t] += add;
    __syncthreads();
  }
  if (t < NBUCK) {
    base[t] = ssc[t] - c;
    gb[t] = c ? atomicAdd(&bfill[t], c) : 0;
  }
  __syncthreads();
  for (int i = t; i < n; i += 256) {
    int r = row[e0 + i];
    int bk = r >> 9;
    int p = base[bk] + atomicAdd(&fil[bk], 1);
    img[p] = make_int2(col[e0 + i] | ((r & 511) << 17),
                       __float_as_int(vals[e0 + i]));
    sbk[p] = (unsigned short)bk;
  }
  __syncthreads();
  for (int i = t; i < n; i += 256) {
    int bk = sbk[i];
    ebuck[bbase[bk] + gb[bk] + (i - base[bk])] = img[i];
  }
}

// K5: per-bucket exact sort + pad-to-8. Rows padded to multiples of 8
// (zero-weight pad edges) so spmm can run an 8-edge unrolled trip with no
// remainder; reserve slack spread +8 over first `units` rows (hole-free).
__global__ __launch_bounds__(256) void bsort_kernel(
    const int* __restrict__ bbase, const int* __restrict__ pbase,
    const int2* __restrict__ ebuck, int2* __restrict__ epack,
    int* __restrict__ row_ptr)
{
  __shared__ int acnt[512], loff[513], lfill[512], ssc[256];
  int b = blockIdx.x, t = threadIdx.x;
  int r0 = b * 512;
  int nr = min(512, N_NODES - r0);
  int eb = bbase[b];
  int ne = bbase[b + 1] - eb;
  int pb = pbase[b];

  acnt[t] = 0; acnt[t + 256] = 0;
  lfill[t] = 0; lfill[t + 256] = 0;
  __syncthreads();
  // phase A: local row histogram
  for (int i = t; i < ne; i += 256)
    atomicAdd(&acnt[((unsigned)ebuck[eb + i].x) >> 17], 1);
  __syncthreads();
  // phase B: padded scan (2 rows per thread), pad-to-8
  int i0 = 2 * t, i1 = 2 * t + 1;
  int a0 = acnt[i0], a1 = acnt[i1];
  int p0 = (a0 + 7) & ~7, p1 = (a1 + 7) & ~7;
  int s = p0 + p1;
  ssc[t] = s;
  __syncthreads();
  for (int off = 1; off < 256; off <<= 1) {
    int add = (t >= off) ? ssc[t - off] : 0;
    __syncthreads();
    ssc[t] += add;
    __syncthreads();
  }
  int ex = ssc[t] - s;
  loff[i0] = ex;
  loff[i1] = ex + p0;
  if (t == 255) loff[512] = ssc[255];
  __syncthreads();
  int T = ssc[255];
  int slack = (pbase[b + 1] - pb) - T;       // multiple of 8, >= 0
  int units = min(slack >> 3, nr);
  if (i0 < nr) row_ptr[r0 + i0] = pb + loff[i0] + 8 * min(i0, units);
  if (i1 < nr) row_ptr[r0 + i1] = pb + loff[i1] + 8 * min(i1, units);
  if (b == NBUCK - 1 && t == 0)
    row_ptr[N_NODES] = pb + loff[nr] + 8 * units;
  __syncthreads();
  // phase C: scatter into private region
  for (int i = t; i < ne; i += 256) {
    int2 ed = ebuck[eb + i];
    int lr = ((unsigned)ed.x) >> 17;
    int cl = ed.x & 0x1FFFF;
    int p = loff[lr] + 8 * min(lr, units) + atomicAdd(&lfill[lr], 1);
    epack[pb + p] = make_int2(cl, ed.y);
  }
  __syncthreads();
  // phase D: zero-weight pad edges (col=0, val=0)
  for (int i = t; i < nr; i += 256) {
    int a = acnt[i];
    int size_i = ((a + 7) & ~7) + 8 * (i < units);
    int st = loff[i] + 8 * min(i, units);
    for (int p = st + a; p < st + size_i; ++p)
      epack[pb + p] = make_int2(0, 0);
  }
}

// ---------------- propagation: xout = 0.9*(A@xin) + 0.1*x0 ----------------
// 8 lanes/row, 4 fp16 channels/lane. Round 5: (a) ep quads loaded
// NONTEMPORAL (epack = 15+ MB/round pure stream, never L2-fits; removing it
// from L2 leaves room for the 6.4 MB xin gather working set); xin/x0h/xout
// stay normally cached (xout is next round's xin!). (b) rows padded to x8 ->
// 8 gathers in flight per trip (2x per-wave MLP for the latency-bound
// gather), ep as 4x dwordx4 per trip.
__global__ __launch_bounds__(256) void spmm_kernel(
    const int* __restrict__ rp, const int2* __restrict__ ep,
    const half_t* __restrict__ xin, const half_t* __restrict__ x0h,
    half_t* __restrict__ xout, float* __restrict__ fout, int last)
{
  int gt = blockIdx.x * 256 + threadIdx.x;
  int r = gt >> 3;
  int c4 = (gt & 7) * 4;
  if (r >= N_NODES) return;
  int e0 = rp[r], e1 = rp[r + 1];

  float acc[4] = {0.f, 0.f, 0.f, 0.f};
  for (int e = e0; e < e1; e += 8) {
    i4v qa = __builtin_nontemporal_load((const i4v*)(ep + e));
    i4v qb = __builtin_nontemporal_load((const i4v*)(ep + e + 2));
    i4v qc = __builtin_nontemporal_load((const i4v*)(ep + e + 4));
    i4v qd = __builtin_nontemporal_load((const i4v*)(ep + e + 6));
    h4 g0 = *(const h4*)(xin + (size_t)qa[0] * D_OUT + c4);
    h4 g1 = *(const h4*)(xin + (size_t)qa[2] * D_OUT + c4);
    h4 g2 = *(const h4*)(xin + (size_t)qb[0] * D_OUT + c4);
    h4 g3 = *(const h4*)(xin + (size_t)qb[2] * D_OUT + c4);
    h4 g4 = *(const h4*)(xin + (size_t)qc[0] * D_OUT + c4);
    h4 g5 = *(const h4*)(xin + (size_t)qc[2] * D_OUT + c4);
    h4 g6 = *(const h4*)(xin + (size_t)qd[0] * D_OUT + c4);
    h4 g7 = *(const h4*)(xin + (size_t)qd[2] * D_OUT + c4);
    float v0 = __int_as_float(qa[1]);
    float v1 = __int_as_float(qa[3]);
    float v2 = __int_as_float(qb[1]);
    float v3 = __int_as_float(qb[3]);
    float v4 = __int_as_float(qc[1]);
    float v5 = __int_as_float(qc[3]);
    float v6 = __int_as_float(qd[1]);
    float v7 = __int_as_float(qd[3]);
#pragma unroll
    for (int j = 0; j < 4; ++j) {
      acc[j] = fmaf(v0, (float)g0[j], acc[j]);
      acc[j] = fmaf(v1, (float)g1[j], acc[j]);
      acc[j] = fmaf(v2, (float)g2[j], acc[j]);
      acc[j] = fmaf(v3, (float)g3[j], acc[j]);
      acc[j] = fmaf(v4, (float)g4[j], acc[j]);
      acc[j] = fmaf(v5, (float)g5[j], acc[j]);
      acc[j] = fmaf(v6, (float)g6[j], acc[j]);
      acc[j] = fmaf(v7, (float)g7[j], acc[j]);
    }
  }

  h4 x0v = *(const h4*)(x0h + (size_t)r * D_OUT + c4);
  if (last) {
    float4 o;
    o.x = 0.9f * acc[0] + 0.1f * (float)x0v[0];
    o.y = 0.9f * acc[1] + 0.1f * (float)x0v[1];
    o.z = 0.9f * acc[2] + 0.1f * (float)x0v[2];
    o.w = 0.9f * acc[3] + 0.1f * (float)x0v[3];
    *(float4*)(fout + (size_t)r * D_OUT + c4) = o;
  } else {
    h4 o;
#pragma unroll
    for (int j = 0; j < 4; ++j)
      o[j] = (half_t)(0.9f * acc[j] + 0.1f * (float)x0v[j]);
    *(h4*)(xout + (size_t)r * D_OUT + c4) = o;
  }
}

extern "C" void kernel_launch(void* const* d_in, const int* in_sizes, int n_in,
                              void* d_out, int out_size, void* d_ws, size_t ws_size,
                              hipStream_t stream) {
  const float* F     = (const float*)d_in[0];
  const int*   row   = (const int*)  d_in[1];
  const int*   col   = (const int*)  d_in[2];
  const float* evals = (const float*)d_in[3];
  const float* W1    = (const float*)d_in[4];
  const float* b1    = (const float*)d_in[5];
  const float* W2    = (const float*)d_in[6];
  const float* b2    = (const float*)d_in[7];
  float* out = (float*)d_out;

  // workspace layout (~44 MB; ws ~410 MB). ebuck aliases P+Q (dead before
  // first spmm writes P). epack enlarged for pad-to-8 (max ~18.4 MB).
  char* w = (char*)d_ws;
  half_t* x0h    = (half_t*)(w);                //  6,400,000
  half_t* P      = (half_t*)(w +  6400000);     //  6,400,000 (alias ebuck lo)
  half_t* Q      = (half_t*)(w + 12800000);     //  6,400,000 (alias ebuck hi)
  int2*   ebuck  = (int2*)  (w +  6400000);     // 12,800,000
  int2*   epack  = (int2*)  (w + 19200000);     // 24,000,000 (padded CSR)
  int*   row_ptr = (int*)   (w + 43200000);     //    400,128 (N+1)
  int*   bcnt    = (int*)   (w + 43600384);     //      1,024 (zeroed)
  int*   bfill   = (int*)   (w + 43601408);     //      1,024 (zeroed)
  int*   bbase   = (int*)   (w + 43602432);     //      1,024
  int*   pbase   = (int*)   (w + 43603456);     //      1,024
  half_t* W1T    = (half_t*)(w + 43604480);     //     32,768
  half_t* W2T    = (half_t*)(w + 43637248);     //      4,096

  // 1) MLP head -> x0 (fp16)
  pack_kernel<<<64, 256, 0, stream>>>(W1, W2, W1T, W2T);
  mlp_kernel<<<(N_NODES / 16 + 3) / 4, 256, 0, stream>>>(F, W1T, b1, W2T, b2, x0h);

  // 2) CSR build (bucketed two-pass sort, rows padded to x8)
  hipMemsetAsync(bcnt, 0, 2048, stream);   // bcnt + bfill
  bhist_kernel<<<640, 256, 0, stream>>>(row, bcnt);
  bscan_kernel<<<1, 256, 0, stream>>>(bcnt, bbase, pbase);
  bscatter_kernel<<<NCHUNK, 256, 0, stream>>>(row, col, evals, bfill, bbase, ebuck);
  bsort_kernel<<<NBUCK, 256, 0, stream>>>(bbase, pbase, ebuck, epack, row_ptr);

  // 3) 10 propagation rounds: x0h -> P -> Q -> ... final writes fp32 d_out
  const int grid_spmm = (N_NODES * 8 + 255) / 256;
  for (int i = 0; i < NPROP; ++i) {
    const half_t* xin = (i == 0) ? x0h : ((i & 1) ? P : Q);
    half_t* xout = (i & 1) ? Q : P;
    int last = (i == NPROP - 1);
    spmm_kernel<<<grid_spmm, 256, 0, stream>>>(
        row_ptr, epack, xin, x0h, xout, out, last);
  }
}

// Round 6
// 531.596 us; speedup vs baseline: 1.1696x; 1.1696x over previous
//
#include <hip/hip_runtime.h>

#define N_NODES 100000
#define N_EDGES 1600000
#define D_IN    256
#define D_HID   64
#define D_OUT   32
#define NPROP   10

#define NBUCK 196          // bucket = row >> 9 (512 rows/bucket)
#define CHUNK 6080         // edges per bscatter block (LDS-limited)
#define NCHUNK ((N_EDGES + CHUNK - 1) / CHUNK)   // 264

typedef _Float16 half_t;
typedef _Float16 h8  __attribute__((ext_vector_type(8)));
typedef _Float16 h4  __attribute__((ext_vector_type(4)));
typedef float    f4v __attribute__((ext_vector_type(4)));

// ---------------- weight pack ----------------
__global__ __launch_bounds__(256) void pack_kernel(
    const float* __restrict__ W1, const float* __restrict__ W2,
    half_t* __restrict__ W1T, half_t* __restrict__ W2T)
{
  int t = blockIdx.x * 256 + threadIdx.x;
  if (t < 64 * 256) { int n = t >> 8, k = t & 255; W1T[t] = (half_t)W1[k * 64 + n]; }
  if (t < 32 * 64)  { int n = t >> 6, k = t & 63;  W2T[t] = (half_t)W2[k * 32 + n]; }
}

// ---------------- MLP head via MFMA ----------------
// Round 6 (single isolated change vs round-1 best): ALL 16 float4 F-loads
// issued up front (one HBM-latency exposure per wave instead of two;
// round-1 profile showed VGPR=36 / VALUBusy 3.4% -> load-serialized).
// launch_bounds(256,2) lets the allocator keep ~100 VGPRs of loads in
// flight. K-order (s*32, s=0..7) identical to round 1 -> bitwise-same out.
#define HSTRIDE 72

__global__ __launch_bounds__(256, 2) void mlp_kernel(
    const float* __restrict__ F, const half_t* __restrict__ W1T,
    const float* __restrict__ b1, const half_t* __restrict__ W2T,
    const float* __restrict__ b2, half_t* __restrict__ x0h)
{
  __shared__ half_t h_lds[4 * 16 * HSTRIDE];   // per-wave 16x64 hidden (pad 72)
  __shared__ half_t out_lds[4 * 16 * 32];      // per-wave 16x32 output
  int t = threadIdx.x;
  int w = t >> 6, lane = t & 63;
  int m = lane & 15, q = lane >> 4;
  int gw = blockIdx.x * 4 + w;
  int node0 = gw * 16;
  if (node0 > N_NODES - 16) node0 = N_NODES - 16;  // tail waves duplicate last tile

  // phase 1: issue ALL F loads (16 x dwordx4 per lane, independent)
  const float* ap = F + (size_t)(node0 + m) * D_IN + q * 8;
  float4 fr[16];
#pragma unroll
  for (int s = 0; s < 8; ++s) {
    fr[2 * s]     = *(const float4*)(ap + s * 32);
    fr[2 * s + 1] = *(const float4*)(ap + s * 32 + 4);
  }

  // phase 2: convert to 8 A-frags (same K-order as round 1: s*32)
  h8 af[8];
#pragma unroll
  for (int s = 0; s < 8; ++s) {
    float4 f0 = fr[2 * s], f1 = fr[2 * s + 1];
    h8 a;
    a[0] = (_Float16)f0.x; a[1] = (_Float16)f0.y;
    a[2] = (_Float16)f0.z; a[3] = (_Float16)f0.w;
    a[4] = (_Float16)f1.x; a[5] = (_Float16)f1.y;
    a[6] = (_Float16)f1.z; a[7] = (_Float16)f1.w;
    af[s] = a;
  }

  // phase 3: 32 MFMAs, A-frags reused across 4 hid-tiles (W1T is L2-hot)
  f4v acc[4];
#pragma unroll
  for (int i = 0; i < 4; ++i) acc[i] = (f4v){0.f, 0.f, 0.f, 0.f};
  const half_t* bp = W1T + (size_t)m * D_IN + q * 8;
#pragma unroll
  for (int s = 0; s < 8; ++s) {
    h8 b0 = *(const h8*)(bp + 0 * 16 * D_IN + s * 32);
    h8 b1v = *(const h8*)(bp + 1 * 16 * D_IN + s * 32);
    h8 b2v = *(const h8*)(bp + 2 * 16 * D_IN + s * 32);
    h8 b3v = *(const h8*)(bp + 3 * 16 * D_IN + s * 32);
    acc[0] = __builtin_amdgcn_mfma_f32_16x16x32_f16(af[s], b0, acc[0], 0, 0, 0);
    acc[1] = __builtin_amdgcn_mfma_f32_16x16x32_f16(af[s], b1v, acc[1], 0, 0, 0);
    acc[2] = __builtin_amdgcn_mfma_f32_16x16x32_f16(af[s], b2v, acc[2], 0, 0, 0);
    acc[3] = __builtin_amdgcn_mfma_f32_16x16x32_f16(af[s], b3v, acc[3], 0, 0, 0);
  }

  half_t* hw = h_lds + w * 16 * HSTRIDE;
#pragma unroll
  for (int ht = 0; ht < 4; ++ht) {
    float bb = b1[ht * 16 + m];
#pragma unroll
    for (int i = 0; i < 4; ++i) {
      float hv = fmaxf(acc[ht][i] + bb, 0.f);
      hw[(q * 4 + i) * HSTRIDE + ht * 16 + m] = (half_t)hv;
    }
  }
  __syncthreads();

  f4v o0 = {0.f, 0.f, 0.f, 0.f}, o1 = {0.f, 0.f, 0.f, 0.f};
#pragma unroll
  for (int s = 0; s < 2; ++s) {
    h8 a = *(const h8*)(hw + m * HSTRIDE + s * 32 + q * 8);
    h8 bb0 = *(const h8*)(W2T + (size_t)m * D_HID + s * 32 + q * 8);
    h8 bb1 = *(const h8*)(W2T + (size_t)(16 + m) * D_HID + s * 32 + q * 8);
    o0 = __builtin_amdgcn_mfma_f32_16x16x32_f16(a, bb0, o0, 0, 0, 0);
    o1 = __builtin_amdgcn_mfma_f32_16x16x32_f16(a, bb1, o1, 0, 0, 0);
  }
  half_t* ow = out_lds + w * 16 * 32;
  {
    float c0 = b2[m], c1 = b2[16 + m];
#pragma unroll
    for (int i = 0; i < 4; ++i) {
      ow[(q * 4 + i) * 32 + m]      = (half_t)(o0[i] + c0);
      ow[(q * 4 + i) * 32 + 16 + m] = (half_t)(o1[i] + c1);
    }
  }
  __syncthreads();

  {
    int nl = lane >> 2, qq = lane & 3;
    *(int4*)(x0h + (size_t)(node0 + nl) * D_OUT + qq * 8) =
        *(const int4*)(ow + nl * 32 + qq * 8);
  }
}

// ---------------- CSR build, two-pass bucketed sort (round-1 exact) ------
__global__ __launch_bounds__(256) void bhist_kernel(
    const int* __restrict__ row, int* __restrict__ bcnt)
{
  __shared__ int lb[NBUCK];
  int t = threadIdx.x;
  for (int i = t; i < NBUCK; i += 256) lb[i] = 0;
  __syncthreads();
  int stride = gridDim.x * 256;
  for (int e = blockIdx.x * 256 + t; e < N_EDGES; e += stride)
    atomicAdd(&lb[row[e] >> 9], 1);
  __syncthreads();
  for (int i = t; i < NBUCK; i += 256)
    if (lb[i]) atomicAdd(&bcnt[i], lb[i]);
}

__global__ __launch_bounds__(256) void bscan_kernel(
    const int* __restrict__ bcnt, int* __restrict__ bbase, int* __restrict__ pbase)
{
  __shared__ int l1[256], l2[256];
  int t = threadIdx.x;
  int a = (t < NBUCK) ? bcnt[t] : 0;
  int r = (t < NBUCK) ? (((a + 3) & ~3) + 3 * 512) : 0;
  l1[t] = a; l2[t] = r;
  __syncthreads();
  for (int off = 1; off < 256; off <<= 1) {
    int x1 = (t >= off) ? l1[t - off] : 0;
    int x2 = (t >= off) ? l2[t - off] : 0;
    __syncthreads();
    l1[t] += x1; l2[t] += x2;
    __syncthreads();
  }
  if (t < NBUCK) { bbase[t] = l1[t] - a; pbase[t] = l2[t] - r; }
  if (t == NBUCK - 1) { bbase[NBUCK] = l1[t]; pbase[NBUCK] = l2[t]; }
}

__global__ __launch_bounds__(256) void bscatter_kernel(
    const int* __restrict__ row, const int* __restrict__ col,
    const float* __restrict__ vals, int* __restrict__ bfill,
    const int* __restrict__ bbase, int2* __restrict__ ebuck)
{
  __shared__ int2 img[CHUNK];                 // 48,640 B
  __shared__ unsigned short sbk[CHUNK];       // 12,160 B
  __shared__ int cnt[NBUCK], base[NBUCK], gb[NBUCK], fil[NBUCK];
  __shared__ int ssc[256];
  int t = threadIdx.x;
  int e0 = blockIdx.x * CHUNK;
  int n = min(CHUNK, N_EDGES - e0);

  for (int i = t; i < NBUCK; i += 256) { cnt[i] = 0; fil[i] = 0; }
  __syncthreads();
  for (int i = t; i < n; i += 256) atomicAdd(&cnt[row[e0 + i] >> 9], 1);
  __syncthreads();
  int c = (t < NBUCK) ? cnt[t] : 0;
  ssc[t] = c;
  __syncthreads();
  for (int off = 1; off < 256; off <<= 1) {
    int add = (t >= off) ? ssc[t - off] : 0;
    __syncthreads();
    ssc[t] += add;
    __syncthreads();
  }
  if (t < NBUCK) {
    base[t] = ssc[t] - c;
    gb[t] = c ? atomicAdd(&bfill[t], c) : 0;
  }
  __syncthreads();
  for (int i = t; i < n; i += 256) {
    int r = row[e0 + i];
    int bk = r >> 9;
    int p = base[bk] + atomicAdd(&fil[bk], 1);
    img[p] = make_int2(col[e0 + i] | ((r & 511) << 17),
                       __float_as_int(vals[e0 + i]));
    sbk[p] = (unsigned short)bk;
  }
  __syncthreads();
  for (int i = t; i < n; i += 256) {
    int bk = sbk[i];
    ebuck[bbase[bk] + gb[bk] + (i - base[bk])] = img[i];
  }
}

// K5: per-bucket exact sort + pad-to-4 (round-1 exact)
__global__ __launch_bounds__(256) void bsort_kernel(
    const int* __restrict__ bbase, const int* __restrict__ pbase,
    const int2* __restrict__ ebuck, int2* __restrict__ epack,
    int* __restrict__ row_ptr)
{
  __shared__ int acnt[512], loff[513], lfill[512], ssc[256];
  int b = blockIdx.x, t = threadIdx.x;
  int r0 = b * 512;
  int nr = min(512, N_NODES - r0);
  int eb = bbase[b];
  int ne = bbase[b + 1] - eb;
  int pb = pbase[b];

  acnt[t] = 0; acnt[t + 256] = 0;
  lfill[t] = 0; lfill[t + 256] = 0;
  __syncthreads();
  for (int i = t; i < ne; i += 256)
    atomicAdd(&acnt[((unsigned)ebuck[eb + i].x) >> 17], 1);
  __syncthreads();
  int i0 = 2 * t, i1 = 2 * t + 1;
  int a0 = acnt[i0], a1 = acnt[i1];
  int p0 = (a0 + 3) & ~3, p1 = (a1 + 3) & ~3;
  int s = p0 + p1;
  ssc[t] = s;
  __syncthreads();
  for (int off = 1; off < 256; off <<= 1) {
    int add = (t >= off) ? ssc[t - off] : 0;
    __syncthreads();
    ssc[t] += add;
    __syncthreads();
  }
  int ex = ssc[t] - s;
  loff[i0] = ex;
  loff[i1] = ex + p0;
  if (t == 255) loff[512] = ssc[255];
  __syncthreads();
  int T = ssc[255];
  int slack = (pbase[b + 1] - pb) - T;
  int units = min(slack >> 2, nr);
  if (i0 < nr) row_ptr[r0 + i0] = pb + loff[i0] + 4 * min(i0, units);
  if (i1 < nr) row_ptr[r0 + i1] = pb + loff[i1] + 4 * min(i1, units);
  if (b == NBUCK - 1 && t == 0)
    row_ptr[N_NODES] = pb + loff[nr] + 4 * units;
  __syncthreads();
  for (int i = t; i < ne; i += 256) {
    int2 ed = ebuck[eb + i];
    int lr = ((unsigned)ed.x) >> 17;
    int cl = ed.x & 0x1FFFF;
    int p = loff[lr] + 4 * min(lr, units) + atomicAdd(&lfill[lr], 1);
    epack[pb + p] = make_int2(cl, ed.y);
  }
  __syncthreads();
  for (int i = t; i < nr; i += 256) {
    int a = acnt[i];
    int size_i = ((a + 3) & ~3) + 4 * (i < units);
    int st = loff[i] + 4 * min(i, units);
    for (int p = st + a; p < st + size_i; ++p)
      epack[pb + p] = make_int2(0, 0);
  }
}

// ---------------- propagation (round-1 exact): 0.9*(A@xin) + 0.1*x0 ------
__global__ __launch_bounds__(256) void spmm_kernel(
    const int* __restrict__ rp, const int2* __restrict__ ep,
    const half_t* __restrict__ xin, const half_t* __restrict__ x0h,
    half_t* __restrict__ xout, float* __restrict__ fout, int last)
{
  int gt = blockIdx.x * 256 + threadIdx.x;
  int r = gt >> 3;
  int c4 = (gt & 7) * 4;
  if (r >= N_NODES) return;
  int e0 = rp[r], e1 = rp[r + 1];

  float acc[4] = {0.f, 0.f, 0.f, 0.f};
  for (int e = e0; e < e1; e += 4) {
    int2 p0 = ep[e];
    int2 p1 = ep[e + 1];
    int2 p2 = ep[e + 2];
    int2 p3 = ep[e + 3];
    h4 g0 = *(const h4*)(xin + (size_t)p0.x * D_OUT + c4);
    h4 g1 = *(const h4*)(xin + (size_t)p1.x * D_OUT + c4);
    h4 g2 = *(const h4*)(xin + (size_t)p2.x * D_OUT + c4);
    h4 g3 = *(const h4*)(xin + (size_t)p3.x * D_OUT + c4);
    float v0 = __int_as_float(p0.y);
    float v1 = __int_as_float(p1.y);
    float v2 = __int_as_float(p2.y);
    float v3 = __int_as_float(p3.y);
#pragma unroll
    for (int j = 0; j < 4; ++j) {
      acc[j] = fmaf(v0, (float)g0[j], acc[j]);
      acc[j] = fmaf(v1, (float)g1[j], acc[j]);
      acc[j] = fmaf(v2, (float)g2[j], acc[j]);
      acc[j] = fmaf(v3, (float)g3[j], acc[j]);
    }
  }

  h4 x0v = *(const h4*)(x0h + (size_t)r * D_OUT + c4);
  if (last) {
    float4 o;
    o.x = 0.9f * acc[0] + 0.1f * (float)x0v[0];
    o.y = 0.9f * acc[1] + 0.1f * (float)x0v[1];
    o.z = 0.9f * acc[2] + 0.1f * (float)x0v[2];
    o.w = 0.9f * acc[3] + 0.1f * (float)x0v[3];
    *(float4*)(fout + (size_t)r * D_OUT + c4) = o;
  } else {
    h4 o;
#pragma unroll
    for (int j = 0; j < 4; ++j)
      o[j] = (half_t)(0.9f * acc[j] + 0.1f * (float)x0v[j]);
    *(h4*)(xout + (size_t)r * D_OUT + c4) = o;
  }
}

extern "C" void kernel_launch(void* const* d_in, const int* in_sizes, int n_in,
                              void* d_out, int out_size, void* d_ws, size_t ws_size,
                              hipStream_t stream) {
  const float* F     = (const float*)d_in[0];
  const int*   row   = (const int*)  d_in[1];
  const int*   col   = (const int*)  d_in[2];
  const float* evals = (const float*)d_in[3];
  const float* W1    = (const float*)d_in[4];
  const float* b1    = (const float*)d_in[5];
  const float* W2    = (const float*)d_in[6];
  const float* b2    = (const float*)d_in[7];
  float* out = (float*)d_out;

  // workspace layout (~35.1 MB). ebuck aliases P+Q: ebuck is dead before the
  // first spmm writes P (stream-ordered).
  char* w = (char*)d_ws;
  half_t* x0h    = (half_t*)(w);                //  6,400,000
  half_t* P      = (half_t*)(w +  6400000);     //  6,400,000 (alias ebuck lo)
  half_t* Q      = (half_t*)(w + 12800000);     //  6,400,000 (alias ebuck hi)
  int2*   ebuck  = (int2*)  (w +  6400000);     // 12,800,000
  int2*   epack  = (int2*)  (w + 19200000);     // 15,400,000 (padded CSR)
  int*   row_ptr = (int*)   (w + 34600192);     //    400,128 (N+1)
  int*   bcnt    = (int*)   (w + 35000576);     //      1,024 (zeroed)
  int*   bfill   = (int*)   (w + 35001600);     //      1,024 (zeroed)
  int*   bbase   = (int*)   (w + 35002624);     //      1,024
  int*   pbase   = (int*)   (w + 35003648);     //      1,024
  half_t* W1T    = (half_t*)(w + 35004672);     //     32,768
  half_t* W2T    = (half_t*)(w + 35037440);     //      4,096

  // 1) MLP head -> x0 (fp16)
  pack_kernel<<<64, 256, 0, stream>>>(W1, W2, W1T, W2T);
  mlp_kernel<<<(N_NODES / 16 + 3) / 4, 256, 0, stream>>>(F, W1T, b1, W2T, b2, x0h);

  // 2) CSR build (bucketed two-pass sort, padded rows)
  hipMemsetAsync(bcnt, 0, 2048, stream);   // bcnt + bfill
  bhist_kernel<<<640, 256, 0, stream>>>(row, bcnt);
  bscan_kernel<<<1, 256, 0, stream>>>(bcnt, bbase, pbase);
  bscatter_kernel<<<NCHUNK, 256, 0, stream>>>(row, col, evals, bfill, bbase, ebuck);
  bsort_kernel<<<NBUCK, 256, 0, stream>>>(bbase, pbase, ebuck, epack, row_ptr);

  // 3) 10 propagation rounds: x0h -> P -> Q -> ... final writes fp32 d_out
  const int grid_spmm = (N_NODES * 8 + 255) / 256;
  for (int i = 0; i < NPROP; ++i) {
    const half_t* xin = (i == 0) ? x0h : ((i & 1) ? P : Q);
    half_t* xout = (i & 1) ? Q : P;
    int last = (i == NPROP - 1);
    spmm_kernel<<<grid_spmm, 256, 0, stream>>>(
        row_ptr, epack, xin, x0h, xout, out, last);
  }
}